// Round 1
// baseline (161.741 us; speedup 1.0000x reference)
//
#include <hip/hip_runtime.h>

#define THREADS 256
#define QPT 2              // queries per thread
#define SLICES 8
#define NPTS 8192
#define BATCH 4
#define SLICE (NPTS / SLICES)   // 1024 targets per block

// ws layout: [2][BATCH][NPTS] uint (float bits) min arrays = 65536 entries = 256 KB

__global__ void chamfer_init(unsigned int* mins) {
    int i = blockIdx.x * blockDim.x + threadIdx.x;
    mins[i] = 0x7F800000u;  // +inf
}

__global__ __launch_bounds__(THREADS) void chamfer_main(
    const float* __restrict__ p1, const float* __restrict__ p2,
    unsigned int* __restrict__ mins)
{
    const int tid  = threadIdx.x;
    const int bz   = blockIdx.z;         // 0..7 : dir*4 + batch
    const int dir  = bz >> 2;
    const int b    = bz & 3;
    const int qbase = blockIdx.x * (THREADS * QPT);
    const int tbase = blockIdx.y * SLICE;

    const float* __restrict__ qsrc = (dir == 0) ? p1 : p2;
    const float* __restrict__ tsrc = (dir == 0) ? p2 : p1;

    // ---- stage transformed targets into LDS: (-2x, -2y, -2z, |t|^2) ----
    __shared__ float4 tgt[SLICE];
    {
        const float* tp = tsrc + ((size_t)b * NPTS + tbase) * 3;
        for (int k = tid; k < SLICE; k += THREADS) {
            float x = tp[k * 3 + 0];
            float y = tp[k * 3 + 1];
            float z = tp[k * 3 + 2];
            tgt[k] = make_float4(-2.0f * x, -2.0f * y, -2.0f * z,
                                 fmaf(x, x, fmaf(y, y, z * z)));
        }
    }

    // ---- load this thread's queries ----
    const int q0 = qbase + tid;
    const int q1 = qbase + THREADS + tid;
    const float* qp0 = qsrc + ((size_t)b * NPTS + q0) * 3;
    const float* qp1 = qsrc + ((size_t)b * NPTS + q1) * 3;
    float ax0 = qp0[0], ay0 = qp0[1], az0 = qp0[2];
    float ax1 = qp1[0], ay1 = qp1[1], az1 = qp1[2];
    float a20 = fmaf(ax0, ax0, fmaf(ay0, ay0, az0 * az0));
    float a21 = fmaf(ax1, ax1, fmaf(ay1, ay1, az1 * az1));

    __syncthreads();

    // ---- main loop: min over targets of (|t|^2 - 2 q.t) ----
    float best0 = 3.0e38f;
    float best1 = 3.0e38f;
#pragma unroll 8
    for (int m = 0; m < SLICE; ++m) {
        float4 t = tgt[m];   // wave-uniform address -> broadcast, conflict-free
        float d0 = fmaf(ax0, t.x, fmaf(ay0, t.y, fmaf(az0, t.z, t.w)));
        float d1 = fmaf(ax1, t.x, fmaf(ay1, t.y, fmaf(az1, t.z, t.w)));
        best0 = fminf(best0, d0);
        best1 = fminf(best1, d1);
    }

    // complete the distance: + |q|^2, clamp tiny negative from cancellation
    float v0 = fmaxf(best0 + a20, 0.0f);
    float v1 = fmaxf(best1 + a21, 0.0f);

    unsigned int* mbase = mins + ((size_t)dir * BATCH + b) * NPTS;
    atomicMin(&mbase[q0], __float_as_uint(v0));
    atomicMin(&mbase[q1], __float_as_uint(v1));
}

__global__ void chamfer_reduce(const unsigned int* __restrict__ mins,
                               float* __restrict__ out)
{
    const int total = 2 * BATCH * NPTS;   // 65536
    float s = 0.0f;
    for (int i = threadIdx.x; i < total; i += THREADS)
        s += __uint_as_float(mins[i]);
#pragma unroll
    for (int off = 32; off >= 1; off >>= 1)
        s += __shfl_down(s, off, 64);
    __shared__ float partial[THREADS / 64];
    if ((threadIdx.x & 63) == 0) partial[threadIdx.x >> 6] = s;
    __syncthreads();
    if (threadIdx.x == 0) {
        float tot = 0.0f;
        for (int w = 0; w < THREADS / 64; ++w) tot += partial[w];
        out[0] = tot * (1.0f / (BATCH * NPTS));
    }
}

extern "C" void kernel_launch(void* const* d_in, const int* in_sizes, int n_in,
                              void* d_out, int out_size, void* d_ws, size_t ws_size,
                              hipStream_t stream) {
    const float* p1 = (const float*)d_in[0];
    const float* p2 = (const float*)d_in[1];
    unsigned int* mins = (unsigned int*)d_ws;   // 65536 uints
    float* out = (float*)d_out;

    // init mins to +inf
    chamfer_init<<<(2 * BATCH * NPTS) / THREADS, THREADS, 0, stream>>>(mins);

    // main: x = query blocks (8192/(256*2)=16), y = target slices, z = dir*4+batch
    dim3 grid(NPTS / (THREADS * QPT), SLICES, 2 * BATCH);
    chamfer_main<<<grid, THREADS, 0, stream>>>(p1, p2, mins);

    // final scalar
    chamfer_reduce<<<1, THREADS, 0, stream>>>(mins, out);
}

// Round 2
// 103.678 us; speedup vs baseline: 1.5600x; 1.5600x over previous
//
#include <hip/hip_runtime.h>

#define THREADS 256
#define QPT 4              // queries per thread
#define SLICES 8
#define NPTS 8192
#define BATCH 4
#define SLICE (NPTS / SLICES)   // 1024 targets per block

// ws layout: [2][BATCH][NPTS] uint (float bits) min arrays = 65536 entries = 256 KB

__global__ void chamfer_init(unsigned int* mins, float* out) {
    int i = blockIdx.x * blockDim.x + threadIdx.x;
    mins[i] = 0x7F800000u;  // +inf
    if (i == 0) out[0] = 0.0f;
}

__global__ __launch_bounds__(THREADS) void chamfer_main(
    const float* __restrict__ p1, const float* __restrict__ p2,
    unsigned int* __restrict__ mins)
{
    const int tid  = threadIdx.x;
    const int bz   = blockIdx.z;         // 0..7 : dir*4 + batch
    const int dir  = bz >> 2;
    const int b    = bz & 3;
    const int qbase = blockIdx.x * (THREADS * QPT);
    const int tbase = blockIdx.y * SLICE;

    const float* __restrict__ qsrc = (dir == 0) ? p1 : p2;
    const float* __restrict__ tsrc = (dir == 0) ? p2 : p1;

    // ---- stage transformed targets into LDS: (-2x, -2y, -2z, |t|^2) ----
    __shared__ float4 tgt[SLICE];
    {
        const float* tp = tsrc + ((size_t)b * NPTS + tbase) * 3;
        for (int k = tid; k < SLICE; k += THREADS) {
            float x = tp[k * 3 + 0];
            float y = tp[k * 3 + 1];
            float z = tp[k * 3 + 2];
            tgt[k] = make_float4(-2.0f * x, -2.0f * y, -2.0f * z,
                                 fmaf(x, x, fmaf(y, y, z * z)));
        }
    }

    // ---- load this thread's queries ----
    float ax[QPT], ay[QPT], az[QPT], a2[QPT], best[QPT];
#pragma unroll
    for (int j = 0; j < QPT; ++j) {
        const int q = qbase + j * THREADS + tid;
        const float* qp = qsrc + ((size_t)b * NPTS + q) * 3;
        ax[j] = qp[0]; ay[j] = qp[1]; az[j] = qp[2];
        a2[j] = fmaf(ax[j], ax[j], fmaf(ay[j], ay[j], az[j] * az[j]));
        best[j] = 3.0e38f;
    }

    __syncthreads();

    // ---- main loop: min over targets of (|t|^2 - 2 q.t) ----
#pragma unroll 4
    for (int m = 0; m < SLICE; ++m) {
        float4 t = tgt[m];   // wave-uniform address -> broadcast, conflict-free
#pragma unroll
        for (int j = 0; j < QPT; ++j) {
            float d = fmaf(ax[j], t.x, fmaf(ay[j], t.y, fmaf(az[j], t.z, t.w)));
            best[j] = fminf(best[j], d);
        }
    }

    // complete the distance: + |q|^2, clamp tiny negative from cancellation
    unsigned int* mbase = mins + ((size_t)dir * BATCH + b) * NPTS;
#pragma unroll
    for (int j = 0; j < QPT; ++j) {
        float v = fmaxf(best[j] + a2[j], 0.0f);
        atomicMin(&mbase[qbase + j * THREADS + tid], __float_as_uint(v));
    }
}

__global__ __launch_bounds__(THREADS) void chamfer_reduce(
    const uint4* __restrict__ mins, float* __restrict__ out)
{
    const int i = blockIdx.x * THREADS + threadIdx.x;   // 64 blocks * 256 = 16384 uint4
    uint4 u = mins[i];
    float s = __uint_as_float(u.x) + __uint_as_float(u.y)
            + __uint_as_float(u.z) + __uint_as_float(u.w);
#pragma unroll
    for (int off = 32; off >= 1; off >>= 1)
        s += __shfl_down(s, off, 64);
    __shared__ float partial[THREADS / 64];
    if ((threadIdx.x & 63) == 0) partial[threadIdx.x >> 6] = s;
    __syncthreads();
    if (threadIdx.x == 0) {
        float tot = 0.0f;
#pragma unroll
        for (int w = 0; w < THREADS / 64; ++w) tot += partial[w];
        atomicAdd(out, tot * (1.0f / (BATCH * NPTS)));
    }
}

extern "C" void kernel_launch(void* const* d_in, const int* in_sizes, int n_in,
                              void* d_out, int out_size, void* d_ws, size_t ws_size,
                              hipStream_t stream) {
    const float* p1 = (const float*)d_in[0];
    const float* p2 = (const float*)d_in[1];
    unsigned int* mins = (unsigned int*)d_ws;   // 65536 uints
    float* out = (float*)d_out;

    // init mins to +inf, out to 0
    chamfer_init<<<(2 * BATCH * NPTS) / THREADS, THREADS, 0, stream>>>(mins, out);

    // main: x = query blocks (8192/(256*4)=8), y = target slices, z = dir*4+batch
    dim3 grid(NPTS / (THREADS * QPT), SLICES, 2 * BATCH);
    chamfer_main<<<grid, THREADS, 0, stream>>>(p1, p2, mins);

    // parallel reduce: 65536 mins / 4 per thread / 256 per block = 64 blocks
    chamfer_reduce<<<(2 * BATCH * NPTS) / (4 * THREADS), THREADS, 0, stream>>>(
        (const uint4*)mins, out);
}

// Round 3
// 98.891 us; speedup vs baseline: 1.6355x; 1.0484x over previous
//
#include <hip/hip_runtime.h>

#define THREADS 256
#define QPT 4              // queries per thread (2 float2 packs)
#define Q2  (QPT / 2)
#define SLICES 16
#define NPTS 8192
#define BATCH 4
#define SLICE (NPTS / SLICES)   // 512 targets per block

typedef float f2 __attribute__((ext_vector_type(2)));

// ws layout: [2][BATCH][NPTS] uint (float bits) min arrays = 65536 entries = 256 KB

__global__ void chamfer_init(unsigned int* mins, float* out) {
    int i = blockIdx.x * blockDim.x + threadIdx.x;
    mins[i] = 0x7F800000u;  // +inf
    if (i == 0) out[0] = 0.0f;
}

__global__ __launch_bounds__(THREADS) void chamfer_main(
    const float* __restrict__ p1, const float* __restrict__ p2,
    unsigned int* __restrict__ mins)
{
    const int tid  = threadIdx.x;
    const int bz   = blockIdx.z;         // 0..7 : dir*4 + batch
    const int dir  = bz >> 2;
    const int b    = bz & 3;
    const int qbase = blockIdx.x * (THREADS * QPT);
    const int tbase = blockIdx.y * SLICE;

    const float* __restrict__ qsrc = (dir == 0) ? p1 : p2;
    const float* __restrict__ tsrc = (dir == 0) ? p2 : p1;

    // ---- stage transformed targets into LDS: (-2x, -2y, -2z, |t|^2) ----
    __shared__ float4 tgt[SLICE];
    {
        const float* tp = tsrc + ((size_t)b * NPTS + tbase) * 3;
        for (int k = tid; k < SLICE; k += THREADS) {
            float x = tp[k * 3 + 0];
            float y = tp[k * 3 + 1];
            float z = tp[k * 3 + 2];
            tgt[k] = make_float4(-2.0f * x, -2.0f * y, -2.0f * z,
                                 fmaf(x, x, fmaf(y, y, z * z)));
        }
    }

    // ---- load this thread's queries, packed 2-wide ----
    f2 ax2[Q2], ay2[Q2], az2[Q2], a2q[Q2], best2[Q2];
#pragma unroll
    for (int j = 0; j < Q2; ++j) {
        const int qa = qbase + (2 * j + 0) * THREADS + tid;
        const int qb = qbase + (2 * j + 1) * THREADS + tid;
        const float* pa = qsrc + ((size_t)b * NPTS + qa) * 3;
        const float* pb = qsrc + ((size_t)b * NPTS + qb) * 3;
        ax2[j] = f2{pa[0], pb[0]};
        ay2[j] = f2{pa[1], pb[1]};
        az2[j] = f2{pa[2], pb[2]};
        a2q[j].x = fmaf(ax2[j].x, ax2[j].x, fmaf(ay2[j].x, ay2[j].x, az2[j].x * az2[j].x));
        a2q[j].y = fmaf(ax2[j].y, ax2[j].y, fmaf(ay2[j].y, ay2[j].y, az2[j].y * az2[j].y));
        best2[j] = f2{3.0e38f, 3.0e38f};
    }

    __syncthreads();

    // ---- main loop: 2 targets/iter, packed FMA over query pairs, min3 fold ----
#pragma unroll 4
    for (int m = 0; m < SLICE; m += 2) {
        float4 ta = tgt[m];
        float4 tb = tgt[m + 1];
        f2 tax = {ta.x, ta.x}, tay = {ta.y, ta.y}, taz = {ta.z, ta.z}, taw = {ta.w, ta.w};
        f2 tbx = {tb.x, tb.x}, tby = {tb.y, tb.y}, tbz = {tb.z, tb.z}, tbw = {tb.w, tb.w};
#pragma unroll
        for (int j = 0; j < Q2; ++j) {
            f2 da = __builtin_elementwise_fma(ax2[j], tax,
                     __builtin_elementwise_fma(ay2[j], tay,
                      __builtin_elementwise_fma(az2[j], taz, taw)));
            f2 db = __builtin_elementwise_fma(ax2[j], tbx,
                     __builtin_elementwise_fma(ay2[j], tby,
                      __builtin_elementwise_fma(az2[j], tbz, tbw)));
            best2[j].x = fminf(fminf(best2[j].x, da.x), db.x);   // -> v_min3_f32
            best2[j].y = fminf(fminf(best2[j].y, da.y), db.y);
        }
    }

    // complete the distance: + |q|^2, clamp tiny negative from cancellation
    unsigned int* mbase = mins + ((size_t)dir * BATCH + b) * NPTS;
#pragma unroll
    for (int j = 0; j < Q2; ++j) {
        float va = fmaxf(best2[j].x + a2q[j].x, 0.0f);
        float vb = fmaxf(best2[j].y + a2q[j].y, 0.0f);
        atomicMin(&mbase[qbase + (2 * j + 0) * THREADS + tid], __float_as_uint(va));
        atomicMin(&mbase[qbase + (2 * j + 1) * THREADS + tid], __float_as_uint(vb));
    }
}

__global__ __launch_bounds__(THREADS) void chamfer_reduce(
    const uint4* __restrict__ mins, float* __restrict__ out)
{
    const int i = blockIdx.x * THREADS + threadIdx.x;   // 64 blocks * 256 = 16384 uint4
    uint4 u = mins[i];
    float s = __uint_as_float(u.x) + __uint_as_float(u.y)
            + __uint_as_float(u.z) + __uint_as_float(u.w);
#pragma unroll
    for (int off = 32; off >= 1; off >>= 1)
        s += __shfl_down(s, off, 64);
    __shared__ float partial[THREADS / 64];
    if ((threadIdx.x & 63) == 0) partial[threadIdx.x >> 6] = s;
    __syncthreads();
    if (threadIdx.x == 0) {
        float tot = 0.0f;
#pragma unroll
        for (int w = 0; w < THREADS / 64; ++w) tot += partial[w];
        atomicAdd(out, tot * (1.0f / (BATCH * NPTS)));
    }
}

extern "C" void kernel_launch(void* const* d_in, const int* in_sizes, int n_in,
                              void* d_out, int out_size, void* d_ws, size_t ws_size,
                              hipStream_t stream) {
    const float* p1 = (const float*)d_in[0];
    const float* p2 = (const float*)d_in[1];
    unsigned int* mins = (unsigned int*)d_ws;   // 65536 uints
    float* out = (float*)d_out;

    // init mins to +inf, out to 0
    chamfer_init<<<(2 * BATCH * NPTS) / THREADS, THREADS, 0, stream>>>(mins, out);

    // main: x = query blocks (8192/(256*4)=8), y = target slices (16), z = dir*4+batch
    dim3 grid(NPTS / (THREADS * QPT), SLICES, 2 * BATCH);
    chamfer_main<<<grid, THREADS, 0, stream>>>(p1, p2, mins);

    // parallel reduce: 65536 mins / 4 per thread / 256 per block = 64 blocks
    chamfer_reduce<<<(2 * BATCH * NPTS) / (4 * THREADS), THREADS, 0, stream>>>(
        (const uint4*)mins, out);
}